// Round 7
// baseline (856.747 us; speedup 1.0000x reference)
//
#include <hip/hip_runtime.h>

constexpr int kB   = 8;
constexpr int kN   = 64;
constexpr int kE   = 192;
constexpr int kDin = 1024;
constexpr int kDp  = 256;
constexpr int kNN  = 4096;
constexpr float kTauInv = 20.0f;

// ---------------------------------------------------------------------------
// Projection GEMM, K-split (z=4), double-buffered LDS, partial out (no bias).
// Block (0,0,0) also zeroes stats (consumed 1 kernel later).
// ---------------------------------------------------------------------------
__global__ __launch_bounds__(256) void gemm_proj(
    const float* __restrict__ x1, const float* __restrict__ x2,
    const float* __restrict__ e1, const float* __restrict__ e2,
    const float* __restrict__ Wp, float* __restrict__ P,
    float* __restrict__ stats)
{
    const int rt = blockIdx.y, ct = blockIdx.x, z = blockIdx.z;
    const int tid = threadIdx.x;
    if (blockIdx.x == 0 && blockIdx.y == 0 && blockIdx.z == 0) {
        for (int i = tid; i < 2048; i += 256) stats[i] = 0.f;
    }
    const int tx = tid & 15, ty = tid >> 4;
    const int grow0 = rt * 64, col0 = ct * 64;

    const float* src; int lrow0;
    if (rt < 8)       { src = x1; lrow0 = grow0; }
    else if (rt < 16) { src = x2; lrow0 = grow0 - 512; }
    else if (rt < 40) { src = e1; lrow0 = grow0 - 1024; }
    else              { src = e2; lrow0 = grow0 - 2560; }

    __shared__ float As[2][16][68];
    __shared__ float Ws[2][16][68];

    const int arow = tid >> 2, acol = (tid & 3) * 4;
    const int wrow = tid >> 4, wcol = (tid & 15) * 4;

    const float* Abase = src + (size_t)(lrow0 + arow) * kDin + z * 256 + acol;
    const float* Wbase = Wp + (size_t)(z * 256 + wrow) * kDp + col0 + wcol;

    float4 a4 = *(const float4*)Abase;
    float4 w4 = *(const float4*)Wbase;

    float acc[4][4] = {};

    for (int c = 0; c < 16; ++c) {
        const int cur = c & 1;
        As[cur][acol + 0][arow] = a4.x;
        As[cur][acol + 1][arow] = a4.y;
        As[cur][acol + 2][arow] = a4.z;
        As[cur][acol + 3][arow] = a4.w;
        *(float4*)&Ws[cur][wrow][wcol] = w4;
        __syncthreads();
        if (c < 15) {
            a4 = *(const float4*)(Abase + (c + 1) * 16);
            w4 = *(const float4*)(Wbase + (size_t)(c + 1) * 16 * kDp);
        }
#pragma unroll
        for (int kk = 0; kk < 16; ++kk) {
            float4 av = *(const float4*)&As[cur][kk][ty * 4];
            float4 wv = *(const float4*)&Ws[cur][kk][tx * 4];
            float a[4] = {av.x, av.y, av.z, av.w};
            float w[4] = {wv.x, wv.y, wv.z, wv.w};
#pragma unroll
            for (int i = 0; i < 4; ++i)
#pragma unroll
                for (int j = 0; j < 4; ++j)
                    acc[i][j] += a[i] * w[j];
        }
    }
    float* Pz = P + (size_t)z * 1048576;
#pragma unroll
    for (int i = 0; i < 4; ++i)
#pragma unroll
        for (int j = 0; j < 4; ++j)
            Pz[(size_t)(grow0 + ty * 4 + i) * kDp + col0 + tx * 4 + j] = acc[i][j];
}

// ---------------------------------------------------------------------------
// Fused: hbuf = sum(P0..P3)+bias  AND  BN stats accumulation (atomics).
// 256 blocks x 16 rows; thread = column.
// ---------------------------------------------------------------------------
__global__ __launch_bounds__(256) void reduce_bias_stats(
    const float* __restrict__ P, const float* __restrict__ bp,
    float* __restrict__ hbuf, float* __restrict__ stats)
{
    const int t = threadIdx.x;
    const int r0 = blockIdx.x * 16;
    const int seg = (r0 < 512) ? 0 : (r0 < 1024 ? 1 : (r0 < 2560 ? 2 : 3));
    const float bb = bp[t];
    float s = 0.f, s2 = 0.f;
#pragma unroll
    for (int rr = 0; rr < 16; ++rr) {
        size_t o = (size_t)(r0 + rr) * kDp + t;
        float v = P[o] + P[o + 1048576] + P[o + 2097152] + P[o + 3145728] + bb;
        hbuf[o] = v;
        s += v; s2 += v * v;
    }
    atomicAdd(&stats[seg * 512 + t], s);
    atomicAdd(&stats[seg * 512 + 256 + t], s2);
}

__global__ __launch_bounds__(256) void bn_norm_l2(float* hbuf,
                                                  const float* __restrict__ stats,
                                                  const float* __restrict__ gamma,
                                                  const float* __restrict__ beta)
{
    int r = blockIdx.x, tid = threadIdx.x;
    int seg = (r < 512) ? 0 : (r < 1024 ? 1 : (r < 2560 ? 2 : 3));
    float n = (seg < 2) ? 512.f : 1536.f;
    float mu   = stats[seg * 512 + tid] / n;
    float var  = stats[seg * 512 + 256 + tid] / n - mu * mu;
    float istd = rsqrtf(var + 1e-5f);
    float v = hbuf[(size_t)r * kDp + tid];
    float p = fmaxf((v - mu) * istd * gamma[tid] + beta[tid], 0.f);
    float ss = p * p;
#pragma unroll
    for (int o = 32; o >= 1; o >>= 1) ss += __shfl_xor(ss, o);
    __shared__ float wsum[4];
    if ((tid & 63) == 0) wsum[tid >> 6] = ss;
    __syncthreads();
    float tot = wsum[0] + wsum[1] + wsum[2] + wsum[3];
    float scale = 1.f / fmaxf(sqrtf(tot), 1e-12f);
    hbuf[(size_t)r * kDp + tid] = p * scale;
}

// ---------------------------------------------------------------------------
// Combined similarity GEMMs: Kp (64x64) and Ke (0.5, 192x192) per batch.
// ---------------------------------------------------------------------------
__global__ __launch_bounds__(256) void gemm_sim(const float* __restrict__ hbuf,
                                                float* __restrict__ Kp,
                                                float* __restrict__ Ke)
{
    const int id = blockIdx.x, b = blockIdx.y, t = threadIdx.x;
    int mt, nt, ldo; const float *X, *Y; float* outp; float scale;
    if (id < 4) {
        mt = (id >> 1) * 32; nt = (id & 1) * 32; ldo = 64;
        X = hbuf + (size_t)b * 64 * kDp;
        Y = hbuf + (512 + (size_t)b * 64) * kDp;
        outp = Kp + (size_t)b * 4096; scale = 1.0f;
    } else {
        int e = id - 4;
        mt = (e / 6) * 32; nt = (e % 6) * 32; ldo = 192;
        X = hbuf + (1024 + (size_t)b * 192) * kDp;
        Y = hbuf + (2560 + (size_t)b * 192) * kDp;
        outp = Ke + (size_t)b * 36864; scale = 0.5f;
    }
    __shared__ float Xs[32][36];
    __shared__ float Ys[32][36];
    const int row = t >> 3, kq = t & 7;
    const int ty = t >> 4, tx = t & 15;
    float acc[2][2] = {};
    for (int k0 = 0; k0 < kDp; k0 += 32) {
        float4 xa = *(const float4*)(X + (size_t)(mt + row) * kDp + k0 + kq * 4);
        float4 ya = *(const float4*)(Y + (size_t)(nt + row) * kDp + k0 + kq * 4);
        Xs[kq * 4 + 0][row] = xa.x; Xs[kq * 4 + 1][row] = xa.y;
        Xs[kq * 4 + 2][row] = xa.z; Xs[kq * 4 + 3][row] = xa.w;
        Ys[kq * 4 + 0][row] = ya.x; Ys[kq * 4 + 1][row] = ya.y;
        Ys[kq * 4 + 2][row] = ya.z; Ys[kq * 4 + 3][row] = ya.w;
        __syncthreads();
#pragma unroll
        for (int kk = 0; kk < 32; ++kk) {
            float2 xv = *(const float2*)&Xs[kk][ty * 2];
            float2 yv = *(const float2*)&Ys[kk][tx * 2];
            acc[0][0] += xv.x * yv.x; acc[0][1] += xv.x * yv.y;
            acc[1][0] += xv.y * yv.x; acc[1][1] += xv.y * yv.y;
        }
        __syncthreads();
    }
#pragma unroll
    for (int i = 0; i < 2; ++i)
#pragma unroll
        for (int j = 0; j < 2; ++j)
            outp[(size_t)(mt + ty * 2 + i) * ldo + nt + tx * 2 + j] = scale * acc[i][j];
}

// ---------------------------------------------------------------------------
// In-LDS sinkhorn iteration via dual potentials. mat untouched; result in fL/gL.
// Compile-time unrolled guarded loops keep register arrays in registers.
// ---------------------------------------------------------------------------
template <int NR, int LANES>
__device__ inline void sink_iter(float (*mat)[68], float* fL, float* gL, int t)
{
    constexpr int MAXK = (NR + LANES - 1) / LANES;
    const int r = t / LANES, s = t % LANES;
    const bool act = r < NR;
    float Lrow[MAXK], Lcol[MAXK];
#pragma unroll
    for (int k = 0; k < MAXK; ++k) {
        int c = s + LANES * k;
        if (c < NR && act) { Lrow[k] = mat[r][c]; Lcol[k] = mat[c][r]; }
        else { Lrow[k] = -1e30f; Lcol[k] = -1e30f; }
    }
    if (t < NR) { fL[t] = 0.f; gL[t] = 0.f; }
    __syncthreads();

    float tv[MAXK];
    for (int it = 0; it < 10; ++it) {
        float mx = -1e30f;
#pragma unroll
        for (int k = 0; k < MAXK; ++k) {
            int c = s + LANES * k;
            tv[k] = (c < NR) ? Lrow[k] + gL[c] : -1e30f;
            mx = fmaxf(mx, tv[k]);
        }
#pragma unroll
        for (int o = 1; o < LANES; o <<= 1) mx = fmaxf(mx, __shfl_xor(mx, o));
        float sum = 0.f;
#pragma unroll
        for (int k = 0; k < MAXK; ++k) {
            int c = s + LANES * k;
            if (c < NR) sum += __expf(tv[k] - mx);
        }
#pragma unroll
        for (int o = 1; o < LANES; o <<= 1) sum += __shfl_xor(sum, o);
        if (act && s == 0) fL[r] = -(mx + __logf(sum));
        __syncthreads();

        mx = -1e30f;
#pragma unroll
        for (int k = 0; k < MAXK; ++k) {
            int c = s + LANES * k;
            tv[k] = (c < NR) ? Lcol[k] + fL[c] : -1e30f;
            mx = fmaxf(mx, tv[k]);
        }
#pragma unroll
        for (int o = 1; o < LANES; o <<= 1) mx = fmaxf(mx, __shfl_xor(mx, o));
        sum = 0.f;
#pragma unroll
        for (int k = 0; k < MAXK; ++k) {
            int c = s + LANES * k;
            if (c < NR) sum += __expf(tv[k] - mx);
        }
#pragma unroll
        for (int o = 1; o < LANES; o <<= 1) sum += __shfl_xor(sum, o);
        if (act && s == 0) gL[r] = -(mx + __logf(sum));
        __syncthreads();
    }
}

// ---------------------------------------------------------------------------
// MEGA: one block per batch. CSR + pairdeg + 3x(layer+sinkhorn) + final
// projection + bordered sinkhorn. All phase transitions are __syncthreads.
// ---------------------------------------------------------------------------
__global__ __launch_bounds__(1024) void mega(
    const int* __restrict__ s1g, const int* __restrict__ d1g,
    const int* __restrict__ s2g, const int* __restrict__ d2g,
    const float* __restrict__ Kp, const float* __restrict__ Ke,
    const float* __restrict__ W0, const float* __restrict__ b0,
    const float* __restrict__ S0, const float* __restrict__ c0,
    const float* __restrict__ W1, const float* __restrict__ b1,
    const float* __restrict__ S1, const float* __restrict__ c1,
    const float* __restrict__ W2, const float* __restrict__ b2,
    const float* __restrict__ S2, const float* __restrict__ c2,
    const float* __restrict__ Wc, const float* __restrict__ bc,
    const float* __restrict__ binvp,
    float* __restrict__ xA, float* __restrict__ xB,
    float* __restrict__ outp)
{
    const int b = blockIdx.x, t = threadIdx.x;

    __shared__ int   ubuf[8516];     // phase A: km1[4096]+km2[4096]; later mat[65][68]+KpL[4096]
    __shared__ int   degcnt[4096];
    __shared__ short es1[kE], ed1[kE], es2[kE], ed2[kE];
    __shared__ short rp1[kE], rp2[kE];
    __shared__ short lst1[kE], lst2[kE], clst1[kE], clst2[kE];
    __shared__ int   off1[65], off2[65], coff1[193], coff2[193];
    __shared__ int   cnt1[64], cnt2[64], ccnt1[kE], ccnt2[kE];
    __shared__ int   pos1[64], pos2[64], cpos1[kE], cpos2[kE];
    __shared__ float fL[65], gL[65];
    __shared__ float WL[17 * 16], bL[16], SL[16];

    int* km1 = ubuf;
    int* km2 = ubuf + 4096;
    float (*mat)[68] = (float (*)[68])ubuf;          // 65*68 = 4420 floats
    float* KpL = (float*)(ubuf + 4420);              // 4096 floats

    // ---- phase A: CSR + class reps ----
    for (int i = t; i < 8192; i += 1024) ubuf[i] = 0x7fffffff;
    for (int i = t; i < 4096; i += 1024) degcnt[i] = 0;
    if (t < 64) { cnt1[t] = 0; cnt2[t] = 0; }
    if (t < kE) {
        ccnt1[t] = 0; ccnt2[t] = 0;
        es1[t] = (short)s1g[b * kE + t]; ed1[t] = (short)d1g[b * kE + t];
        es2[t] = (short)s2g[b * kE + t]; ed2[t] = (short)d2g[b * kE + t];
    }
    __syncthreads();
    if (t < kE) {
        atomicAdd(&cnt1[es1[t]], 1);
        atomicAdd(&cnt2[es2[t]], 1);
        atomicMin(&km1[es1[t] * 64 + ed1[t]], t);
        atomicMin(&km2[es2[t] * 64 + ed2[t]], t);
    }
    __syncthreads();
    if (t < kE) {
        int r1 = km1[es1[t] * 64 + ed1[t]];
        int r2 = km2[es2[t] * 64 + ed2[t]];
        rp1[t] = (short)r1; rp2[t] = (short)r2;
        atomicAdd(&ccnt1[r1], 1);
        atomicAdd(&ccnt2[r2], 1);
    }
    __syncthreads();
    if (t == 0)      { int a = 0; for (int v = 0; v < 64; ++v) { off1[v] = a; pos1[v] = a; a += cnt1[v]; } off1[64] = kE; }
    else if (t == 1) { int a = 0; for (int v = 0; v < 64; ++v) { off2[v] = a; pos2[v] = a; a += cnt2[v]; } off2[64] = kE; }
    else if (t == 2) { int a = 0; for (int v = 0; v < kE; ++v) { coff1[v] = a; cpos1[v] = a; a += ccnt1[v]; } coff1[kE] = kE; }
    else if (t == 3) { int a = 0; for (int v = 0; v < kE; ++v) { coff2[v] = a; cpos2[v] = a; a += ccnt2[v]; } coff2[kE] = kE; }
    __syncthreads();
    if (t < kE) {
        int p = atomicAdd(&pos1[es1[t]], 1);  lst1[p] = (short)t;
        int q = atomicAdd(&pos2[es2[t]], 1);  lst2[q] = (short)t;
        int cp = atomicAdd(&cpos1[rp1[t]], 1); clst1[cp] = (short)t;
        int cq = atomicAdd(&cpos2[rp2[t]], 1); clst2[cq] = (short)t;
    }
    __syncthreads();

    // ---- phase B: degree counting (LDS atomics only) ----
    const float* Keb = Ke + (size_t)b * kE * kE;
    for (int idx = t; idx < kE * kE; idx += 1024) {
        int i = idx / kE, j = idx - i * kE;
        if (rp1[i] != i || rp2[j] != j) continue;
        float sum = 0.f;
        for (int m = coff1[i]; m < coff1[i + 1]; ++m) {
            const float* kr = Keb + (size_t)clst1[m] * kE;
            for (int n = coff2[j]; n < coff2[j + 1]; ++n) sum += kr[clst2[n]];
        }
        int r = es2[j] * 64 + es1[i];
        int c = ed2[j] * 64 + ed1[i];
        if (r != c && sum > 0.f) atomicAdd(&degcnt[r], 1);
    }
    __syncthreads();   // km1/km2 dead beyond this point

    // ---- load Kp tile into LDS (overlays km region) ----
    for (int i = t; i < 4096; i += 1024) KpL[i] = Kp[(size_t)b * 4096 + i];
    if (t < 16) { bL[t] = b0[t]; SL[t] = S0[t]; WL[t] = W0[t]; }
    __syncthreads();

    float* xAb = xA + (size_t)b * kNN * 17;
    float* xBb = xB + (size_t)b * kNN * 17;

    // ---- layer 0 (C=1, x = Kp^T) ----
    {
        float c0v = c0[0];
        for (int row = t; row < kNN; row += 1024) {
            int r2 = row >> 6, r1 = row & 63;
            float msg = 0.f;
            for (int kk = off2[r2]; kk < off2[r2 + 1]; ++kk) {
                int j = lst2[kk]; int dd2 = ed2[j];
                for (int m = off1[r1]; m < off1[r1 + 1]; ++m) {
                    int i = lst1[m]; int dd1 = ed1[i];
                    if (dd2 == r2 && dd1 == r1) continue;
                    msg += Keb[(size_t)i * kE + j] * KpL[dd1 * 64 + dd2];
                }
            }
            float kd = KpL[r1 * 64 + r2];
            float dg = fmaxf((float)(degcnt[row] + (kd > 0.f ? 1 : 0)), 1.f);
            float mv = (msg + kd * kd) / dg;
            float v = c0v;
            float* xo = xAb + (size_t)row * 17;
#pragma unroll
            for (int f = 0; f < 16; ++f) {
                float h = fmaxf(mv * WL[f] + bL[f], 0.f);
                xo[f] = h; v += h * SL[f];
            }
            mat[r1][r2] = v * kTauInv;
        }
        __syncthreads();
        sink_iter<64, 16>(mat, fL, gL, t);
        for (int idx = t; idx < kNN; idx += 1024) {
            int p = idx >> 6, q = idx & 63;
            xAb[(size_t)(q * 64 + p) * 17 + 16] = __expf(mat[p][q] + fL[p] + gL[q]);
        }
        __syncthreads();
    }

    // ---- layers 1 & 2 (C=17) ----
    for (int layer = 0; layer < 2; ++layer) {
        const float* Wg = layer ? W2 : W1;
        const float* bg = layer ? b2 : b1;
        const float* Sg = layer ? S2 : S1;
        const float* cg = layer ? c2 : c1;
        const float* xin  = layer ? xBb : xAb;
        float*       xout = layer ? xAb : xBb;
        for (int k = t; k < 17 * 16; k += 1024) WL[k] = Wg[k];
        if (t < 16) { bL[t] = bg[t]; SL[t] = Sg[t]; }
        __syncthreads();
        float c0v = cg[0];
        for (int row = t; row < kNN; row += 1024) {
            int r2 = row >> 6, r1 = row & 63;
            float msg[17];
#pragma unroll
            for (int c = 0; c < 17; ++c) msg[c] = 0.f;
            for (int kk = off2[r2]; kk < off2[r2 + 1]; ++kk) {
                int j = lst2[kk]; int dd2 = ed2[j];
                for (int m = off1[r1]; m < off1[r1 + 1]; ++m) {
                    int i = lst1[m]; int dd1 = ed1[i];
                    if (dd2 == r2 && dd1 == r1) continue;
                    float kv = Keb[(size_t)i * kE + j];
                    const float* xc = xin + (size_t)(dd2 * 64 + dd1) * 17;
#pragma unroll
                    for (int c = 0; c < 17; ++c) msg[c] += kv * xc[c];
                }
            }
            float kd = KpL[r1 * 64 + r2];
            float dg = fmaxf((float)(degcnt[row] + (kd > 0.f ? 1 : 0)), 1.f);
            float inv = 1.f / dg;
            const float* xr = xin + (size_t)row * 17;
#pragma unroll
            for (int c = 0; c < 17; ++c) msg[c] = (msg[c] + kd * xr[c]) * inv;
            float v = c0v;
            float* xo = xout + (size_t)row * 17;
#pragma unroll
            for (int f = 0; f < 16; ++f) {
                float a = bL[f];
#pragma unroll
                for (int c = 0; c < 17; ++c) a += msg[c] * WL[c * 16 + f];
                float h = fmaxf(a, 0.f);
                xo[f] = h; v += h * SL[f];
            }
            mat[r1][r2] = v * kTauInv;
        }
        __syncthreads();
        sink_iter<64, 16>(mat, fL, gL, t);
        for (int idx = t; idx < kNN; idx += 1024) {
            int p = idx >> 6, q = idx & 63;
            xout[(size_t)(q * 64 + p) * 17 + 16] = __expf(mat[p][q] + fL[p] + gL[q]);
        }
        __syncthreads();
    }

    // ---- final projection + bordered sinkhorn ----
    {
        if (t < 17) WL[t] = Wc[t];
        __syncthreads();
        float bcv = bc[0], binvv = binvp[0];
        for (int row = t; row < kNN; row += 1024) {
            int r2 = row >> 6, r1 = row & 63;
            const float* xr = xAb + (size_t)row * 17;
            float v = bcv;
#pragma unroll
            for (int c = 0; c < 17; ++c) v += xr[c] * WL[c];
            mat[r1][r2] = v;
        }
        if (t < 65) { mat[t][64] = binvv; mat[64][t] = binvv; }
        __syncthreads();
        sink_iter<65, 8>(mat, fL, gL, t);
        for (int idx = t; idx < kNN; idx += 1024) {
            int p = idx >> 6, q = idx & 63;
            outp[(size_t)b * kNN + p * 64 + q] = __expf(mat[p][q] + fL[p] + gL[q]);
        }
    }
}

// ---------------------------------------------------------------------------
// Single-block global max + normalize.
// ---------------------------------------------------------------------------
__global__ __launch_bounds__(1024) void norm_out(float* __restrict__ outp)
{
    const int t = threadIdx.x;
    float4 v[8];
    float mx = -1e30f;
#pragma unroll
    for (int i = 0; i < 8; ++i) {
        v[i] = ((const float4*)outp)[t + i * 1024];
        mx = fmaxf(mx, fmaxf(fmaxf(v[i].x, v[i].y), fmaxf(v[i].z, v[i].w)));
    }
#pragma unroll
    for (int o = 32; o >= 1; o >>= 1) mx = fmaxf(mx, __shfl_xor(mx, o));
    __shared__ float wmax[16];
    if ((t & 63) == 0) wmax[t >> 6] = mx;
    __syncthreads();
    if (t < 16) {
        float m2 = wmax[t];
#pragma unroll
        for (int o = 8; o >= 1; o >>= 1) m2 = fmaxf(m2, __shfl_xor(m2, o));
        if (t == 0) wmax[0] = m2;
    }
    __syncthreads();
    float inv = 1.0f / wmax[0];
#pragma unroll
    for (int i = 0; i < 8; ++i) {
        float4 r;
        r.x = v[i].x * inv; r.y = v[i].y * inv;
        r.z = v[i].z * inv; r.w = v[i].w * inv;
        ((float4*)outp)[t + i * 1024] = r;
    }
}

// ---------------------------------------------------------------------------
extern "C" void kernel_launch(void* const* d_in, const int* in_sizes, int n_in,
                              void* d_out, int out_size, void* d_ws, size_t ws_size,
                              hipStream_t stream)
{
    (void)in_sizes; (void)n_in; (void)out_size; (void)ws_size;

    const float* x1    = (const float*)d_in[0];
    const float* x2    = (const float*)d_in[1];
    const float* e1    = (const float*)d_in[2];
    const float* e2    = (const float*)d_in[3];
    const float* Wp    = (const float*)d_in[4];
    const float* bp    = (const float*)d_in[5];
    const float* gamma = (const float*)d_in[6];
    const float* beta  = (const float*)d_in[7];
    const float* W0 = (const float*)d_in[8];
    const float* b0 = (const float*)d_in[9];
    const float* S0 = (const float*)d_in[10];
    const float* c0 = (const float*)d_in[11];
    const float* W1 = (const float*)d_in[12];
    const float* b1 = (const float*)d_in[13];
    const float* S1 = (const float*)d_in[14];
    const float* c1 = (const float*)d_in[15];
    const float* W2 = (const float*)d_in[16];
    const float* b2 = (const float*)d_in[17];
    const float* S2 = (const float*)d_in[18];
    const float* c2 = (const float*)d_in[19];
    const float* Wc = (const float*)d_in[20];
    const float* bc = (const float*)d_in[21];
    const float* binv = (const float*)d_in[22];
    const int* src1 = (const int*)d_in[23];
    const int* dst1 = (const int*)d_in[24];
    const int* src2 = (const int*)d_in[25];
    const int* dst2 = (const int*)d_in[26];

    float* out = (float*)d_out;
    float* wsf = (float*)d_ws;

    float* hbuf  = wsf;                    // 1,048,576
    float* P     = hbuf + 1048576;         // 4,194,304
    float* Kp    = P + 4194304;            // 32768
    float* Ke    = Kp + 32768;             // 294912
    float* xA    = Ke + 294912;            // 557056
    float* xB    = xA + 557056;            // 557056
    float* stats = xB + 557056;            // 2048

    // ---- projection GEMM (zeroes stats in block 0) + fused reduce+stats ----
    gemm_proj<<<dim3(4, 64, 4), 256, 0, stream>>>(x1, x2, e1, e2, Wp, P, stats);
    reduce_bias_stats<<<256, 256, 0, stream>>>(P, bp, hbuf, stats);

    // ---- batchnorm + relu + l2norm ----
    bn_norm_l2<<<4096, 256, 0, stream>>>(hbuf, stats, gamma, beta);

    // ---- similarity GEMMs ----
    gemm_sim<<<dim3(40, 8), 256, 0, stream>>>(hbuf, Kp, Ke);

    // ---- everything per-batch in one kernel ----
    mega<<<8, 1024, 0, stream>>>(src1, dst1, src2, dst2, Kp, Ke,
                                 W0, b0, S0, c0, W1, b1, S1, c1, W2, b2, S2, c2,
                                 Wc, bc, binv, xA, xB, out);

    // ---- global max normalize ----
    norm_out<<<1, 1024, 0, stream>>>(out);
}